// Round 1
// baseline (184.090 us; speedup 1.0000x reference)
//
#include <hip/hip_runtime.h>

// Problem constants (from reference setup_inputs)
#define F_FACES 6144
#define VN      5000
#define BATCH   2

// log2(e)
#define L2E_F   1.4426950408889634f
// sqrt(625 * log2(e))  -- C pre-scale so exp2 arg = ai + aj + 2*dot(C'i,C'j)
#define SC_F    30.02806022f
// sqrt(4 * log2(e))    -- N pre-scale so exp2 arg = dot(N'i,N'j) - 4*log2(e)
#define SN_F    2.40224481f
// 4 * log2(e)
#define C4_F    5.77078016f

__device__ __forceinline__ float fast_exp2(float x) {
#if defined(__has_builtin)
#if __has_builtin(__builtin_amdgcn_exp2f)
    return __builtin_amdgcn_exp2f(x);
#else
    return exp2f(x);
#endif
#else
    return exp2f(x);
#endif
}

// ---------------------------------------------------------------------------
// Kernel 1: per-face mesh quantities for all 4 meshes (b in {0,1} x {pred,targ})
// Stores per face, AoS of two float4:
//   [Cx*SC, Cy*SC, Cz*SC, -(|C*SC|^2)]  and  [Nx*inv*SN, Ny*inv*SN, Nz*inv*SN, L]
// Also zeroes the output accumulator (stream-ordered before kernel 2).
// ---------------------------------------------------------------------------
__global__ __launch_bounds__(256) void mesh_prep(
    const float* __restrict__ pred, const float* __restrict__ targ,
    const int* __restrict__ faces, float4* __restrict__ ws4,
    float* __restrict__ out)
{
    const int f = blockIdx.x * 256 + threadIdx.x;
    const int m = blockIdx.y;                    // mesh id = b*2 + which
    if (blockIdx.x == 0 && m == 0 && threadIdx.x == 0) out[0] = 0.0f;
    if (f >= F_FACES) return;

    const int b = m >> 1, which = m & 1;
    const float* V = (which ? targ : pred) + b * (VN * 3);

    const int i0 = faces[3 * f + 0];
    const int i1 = faces[3 * f + 1];
    const int i2 = faces[3 * f + 2];

    const float v0x = V[3 * i0 + 0], v0y = V[3 * i0 + 1], v0z = V[3 * i0 + 2];
    const float v1x = V[3 * i1 + 0], v1y = V[3 * i1 + 1], v1z = V[3 * i1 + 2];
    const float v2x = V[3 * i2 + 0], v2y = V[3 * i2 + 1], v2z = V[3 * i2 + 2];

    const float Cx = (v0x + v1x + v2x) * (1.0f / 3.0f);
    const float Cy = (v0y + v1y + v2y) * (1.0f / 3.0f);
    const float Cz = (v0z + v1z + v2z) * (1.0f / 3.0f);

    const float e1x = v1x - v0x, e1y = v1y - v0y, e1z = v1z - v0z;
    const float e2x = v2x - v0x, e2y = v2y - v0y, e2z = v2z - v0z;

    const float Nx = 0.5f * (e1y * e2z - e1z * e2y);
    const float Ny = 0.5f * (e1z * e2x - e1x * e2z);
    const float Nz = 0.5f * (e1x * e2y - e1y * e2x);

    const float l2  = Nx * Nx + Ny * Ny + Nz * Nz + 1e-24f;
    const float L   = sqrtf(l2);
    const float inv = 1.0f / L;

    const float Csx = Cx * SC_F, Csy = Cy * SC_F, Csz = Cz * SC_F;
    const float a   = -(Csx * Csx + Csy * Csy + Csz * Csz);
    const float s   = inv * SN_F;

    const long base = (long)(m * F_FACES + f) * 2;
    ws4[base + 0] = make_float4(Csx, Csy, Csz, a);
    ws4[base + 1] = make_float4(Nx * s, Ny * s, Nz * s, L);
}

// ---------------------------------------------------------------------------
// Kernel 2: pair sums.
// grid.x = iTiles(6) * jChunks(24); grid.y = 6 (b x {ss, st, tt})
// Each thread owns IT=4 i-faces (registers); j-tile of 256 staged in LDS
// (all lanes read same LDS address -> broadcast, conflict-free).
// Per pair: 18 VALU + 2 v_exp_f32.
//   contribution = Li*Lj * exp2(an) * (t^4 + 0.25 t^16 + 0.16 t^25),
//   t = exp2(ai + aj + 2*dotC'), an = dot(N'i,N'j) - 4*log2e
// ---------------------------------------------------------------------------
#define IT        4
#define TJ        256
#define J_CHUNKS  24
#define I_TILES   (F_FACES / (256 * IT))   // 6

__global__ __launch_bounds__(256) void varifold_pairs(
    const float4* __restrict__ ws4, float* __restrict__ out)
{
    __shared__ float4 sA[TJ];
    __shared__ float4 sB[TJ];
    __shared__ float  red[4];

    const int tid = threadIdx.x;
    const int it  = blockIdx.x / J_CHUNKS;   // 0..5
    const int jc  = blockIdx.x % J_CHUNKS;   // 0..23
    const int cb  = blockIdx.y;              // 0..5
    const int b   = cb / 3, c = cb % 3;      // c: 0=ss 1=st 2=tt
    const int m1  = b * 2 + (c == 2 ? 1 : 0);
    const int m2  = b * 2 + (c >= 1 ? 1 : 0);
    const float weight = (c == 1) ? -1.0f : 0.5f;   // includes 1/B = 0.5

    const float4* P1 = ws4 + (long)m1 * (F_FACES * 2);
    const float4* P2 = ws4 + (long)m2 * (F_FACES * 2);

    float Cix[IT], Ciy[IT], Ciz[IT], Ai[IT];
    float Nix[IT], Niy[IT], Niz[IT], Li[IT];
    float acc[IT];

#pragma unroll
    for (int k = 0; k < IT; ++k) {
        const int i = it * (256 * IT) + k * 256 + tid;
        const float4 A  = P1[2 * i + 0];
        const float4 Bv = P1[2 * i + 1];
        Cix[k] = A.x; Ciy[k] = A.y; Ciz[k] = A.z; Ai[k] = A.w;
        Nix[k] = Bv.x; Niy[k] = Bv.y; Niz[k] = Bv.z; Li[k] = Bv.w;
        acc[k] = 0.0f;
    }

    // stage this block's j-tile (TJ = 256 faces = one cooperative load)
    const int j0 = jc * TJ;
    sA[tid] = P2[2 * (j0 + tid) + 0];
    sB[tid] = P2[2 * (j0 + tid) + 1];
    __syncthreads();

#pragma unroll 4
    for (int jj = 0; jj < TJ; ++jj) {
        const float4 a4 = sA[jj];
        const float4 b4 = sB[jj];
#pragma unroll
        for (int k = 0; k < IT; ++k) {
            // exp2 arg for distance kernel: ai + aj + 2*dot(C'i, C'j)
            float dot = Cix[k] * a4.x;
            dot = fmaf(Ciy[k], a4.y, dot);
            dot = fmaf(Ciz[k], a4.z, dot);
            const float argt = fmaf(2.0f, dot, Ai[k] + a4.w);
            const float t0 = fast_exp2(argt);          // exp(-625*d2)
            // exp2 arg for normal kernel: dot(N'i, N'j) - 4*log2e
            float argn = fmaf(Nix[k], b4.x, -C4_F);
            argn = fmaf(Niy[k], b4.y, argn);
            argn = fmaf(Niz[k], b4.z, argn);
            const float en = fast_exp2(argn);          // exp(4*(ndot-1))
            // sigma powers: t^4, t^16, t^25
            const float t2  = t0 * t0;
            const float t4  = t2 * t2;
            const float t8  = t4 * t4;
            const float t16 = t8 * t8;
            const float t25 = t16 * t8 * t0;
            float p = fmaf(0.25f, t16, t4);
            p = fmaf(0.16f, t25, p);
            acc[k] = fmaf(b4.w, en * p, acc[k]);       // += Lj * en * poly
        }
    }

    // epilogue: apply Li, reduce block, one atomic
    float part = 0.0f;
#pragma unroll
    for (int k = 0; k < IT; ++k) part = fmaf(acc[k], Li[k], part);

#pragma unroll
    for (int off = 32; off; off >>= 1) part += __shfl_xor(part, off);
    if ((tid & 63) == 0) red[tid >> 6] = part;
    __syncthreads();
    if (tid == 0) atomicAdd(out, weight * (red[0] + red[1] + red[2] + red[3]));
}

// ---------------------------------------------------------------------------
extern "C" void kernel_launch(void* const* d_in, const int* in_sizes, int n_in,
                              void* d_out, int out_size, void* d_ws, size_t ws_size,
                              hipStream_t stream) {
    const float* pred  = (const float*)d_in[0];
    const float* targ  = (const float*)d_in[1];
    const int*   faces = (const int*)d_in[2];
    float*       out   = (float*)d_out;
    float4*      ws4   = (float4*)d_ws;   // needs 4*6144*2*16 = 786432 B

    dim3 g1(F_FACES / 256, 2 * BATCH);
    mesh_prep<<<g1, 256, 0, stream>>>(pred, targ, faces, ws4, out);

    dim3 g2(I_TILES * J_CHUNKS, 3 * BATCH);
    varifold_pairs<<<g2, 256, 0, stream>>>(ws4, out);
}

// Round 2
// 157.619 us; speedup vs baseline: 1.1679x; 1.1679x over previous
//
#include <hip/hip_runtime.h>

// Problem constants (from reference setup_inputs)
#define F_FACES 6144
#define VN      5000
#define BATCH   2

// sqrt(625 * log2(e))  -- C pre-scale: exp2 arg = ai + aj + 2*dot(C'i,C'j)
#define SC_F    30.02806022f
// sqrt(4 * log2(e))    -- N pre-scale: ndot term = dot(N'i,N'j)
#define SN_F    2.40224481f
// 4 * log2(e)
#define C4_F    5.7707801635558535f

// Raw v_exp_f32 — guaranteed, no libm range-reduction overhead.
__device__ __forceinline__ float fast_exp2(float x) {
    float r;
    asm("v_exp_f32 %0, %1" : "=v"(r) : "v"(x));
    return r;
}

// ---------------------------------------------------------------------------
// Kernel 1: per-face mesh quantities for all 4 meshes (b in {0,1} x {pred,targ})
// Per face, two float4:
//   A = [Cx*SC, Cy*SC, Cz*SC, -|C*SC|^2]
//   B = [Nx*inv*SN, Ny*inv*SN, Nz*inv*SN, log2(L) - 4*log2e]
// The B.w trick folds Lj AND the -4*log2e constant into the normal-kernel
// exp2, so the pair loop needs no extra multiply for Lj and no constant add.
// Also zeroes the output accumulator (stream-ordered before kernel 2).
// ---------------------------------------------------------------------------
__global__ __launch_bounds__(256) void mesh_prep(
    const float* __restrict__ pred, const float* __restrict__ targ,
    const int* __restrict__ faces, float4* __restrict__ ws4,
    float* __restrict__ out)
{
    const int f = blockIdx.x * 256 + threadIdx.x;
    const int m = blockIdx.y;                    // mesh id = b*2 + which
    if (blockIdx.x == 0 && m == 0 && threadIdx.x == 0) out[0] = 0.0f;
    if (f >= F_FACES) return;

    const int b = m >> 1, which = m & 1;
    const float* V = (which ? targ : pred) + b * (VN * 3);

    const int i0 = faces[3 * f + 0];
    const int i1 = faces[3 * f + 1];
    const int i2 = faces[3 * f + 2];

    const float v0x = V[3 * i0 + 0], v0y = V[3 * i0 + 1], v0z = V[3 * i0 + 2];
    const float v1x = V[3 * i1 + 0], v1y = V[3 * i1 + 1], v1z = V[3 * i1 + 2];
    const float v2x = V[3 * i2 + 0], v2y = V[3 * i2 + 1], v2z = V[3 * i2 + 2];

    const float Cx = (v0x + v1x + v2x) * (1.0f / 3.0f);
    const float Cy = (v0y + v1y + v2y) * (1.0f / 3.0f);
    const float Cz = (v0z + v1z + v2z) * (1.0f / 3.0f);

    const float e1x = v1x - v0x, e1y = v1y - v0y, e1z = v1z - v0z;
    const float e2x = v2x - v0x, e2y = v2y - v0y, e2z = v2z - v0z;

    const float Nx = 0.5f * (e1y * e2z - e1z * e2y);
    const float Ny = 0.5f * (e1z * e2x - e1x * e2z);
    const float Nz = 0.5f * (e1x * e2y - e1y * e2x);

    const float l2  = Nx * Nx + Ny * Ny + Nz * Nz + 1e-24f;
    const float L   = sqrtf(l2);
    const float inv = 1.0f / L;

    const float Csx = Cx * SC_F, Csy = Cy * SC_F, Csz = Cz * SC_F;
    const float a   = -(Csx * Csx + Csy * Csy + Csz * Csz);
    const float s   = inv * SN_F;

    const long base = (long)(m * F_FACES + f) * 2;
    ws4[base + 0] = make_float4(Csx, Csy, Csz, a);
    ws4[base + 1] = make_float4(Nx * s, Ny * s, Nz * s, log2f(L) - C4_F);
}

// ---------------------------------------------------------------------------
// Kernel 2: pair sums.
// grid.x = I_TILES(6) * J_CHUNKS(48) = 288; grid.y = 6 (b x {ss, st, tt})
// -> 1728 blocks (~6.75/CU, ~27 waves/CU co-resident) for latency hiding.
// Each thread owns IT=4 i-faces in registers (i-side C pre-doubled so the
// argt chain starts from a_j); j-tile of 128 faces staged in LDS (broadcast
// reads, conflict-free).
// Per pair: 16 VALU + 2 v_exp_f32:
//   argt = fma(C2ix,Cjx, fma(C2iy,Cjy, fma(C2iz,Cjz, aj))) + ai   (3 fma + add)
//   t    = exp2(argt)                                  = exp(-625*d2)
//   argn = fma(Nix,Njx, fma(Niy,Njy, fma(Niz,Njz, wj)))           (3 fma)
//   en   = exp2(argn)                                  = Lj*exp(4*(ndot-1))
//   powers t2,t4,t8,t16,t24,t25 (6 mul), poly 2 fma, acc 1 fma
// ---------------------------------------------------------------------------
#define IT        4
#define TJ        128
#define J_CHUNKS  (F_FACES / TJ)          // 48
#define I_TILES   (F_FACES / (256 * IT))  // 6

__global__ __launch_bounds__(256) void varifold_pairs(
    const float4* __restrict__ ws4, float* __restrict__ out)
{
    __shared__ float4 sAB[2 * TJ];   // interleaved A,B per face
    __shared__ float  red[4];

    const int tid = threadIdx.x;
    const int it  = blockIdx.x / J_CHUNKS;   // 0..5
    const int jc  = blockIdx.x % J_CHUNKS;   // 0..47
    const int cb  = blockIdx.y;              // 0..5
    const int b   = cb / 3, c = cb % 3;      // c: 0=ss 1=st 2=tt
    const int m1  = b * 2 + (c == 2 ? 1 : 0);
    const int m2  = b * 2 + (c >= 1 ? 1 : 0);
    const float weight = (c == 1) ? -1.0f : 0.5f;   // includes 1/B = 0.5

    const float4* P1 = ws4 + (long)m1 * (F_FACES * 2);
    const float4* P2 = ws4 + (long)m2 * (F_FACES * 2);

    float C2x[IT], C2y[IT], C2z[IT], Ai[IT];
    float Nix[IT], Niy[IT], Niz[IT], Li[IT];
    float acc[IT];

#pragma unroll
    for (int k = 0; k < IT; ++k) {
        const int i = it * (256 * IT) + k * 256 + tid;
        const float4 A  = P1[2 * i + 0];
        const float4 Bv = P1[2 * i + 1];
        C2x[k] = 2.0f * A.x; C2y[k] = 2.0f * A.y; C2z[k] = 2.0f * A.z;
        Ai[k]  = A.w;
        Nix[k] = Bv.x; Niy[k] = Bv.y; Niz[k] = Bv.z;
        Li[k]  = fast_exp2(Bv.w + C4_F);   // recover Li = exp2(log2 Li)
        acc[k] = 0.0f;
    }

    // stage this block's j-tile: 2*TJ = 256 float4 = one load per thread
    sAB[tid] = P2[2 * (jc * TJ) + tid];
    __syncthreads();

#pragma unroll 4
    for (int jj = 0; jj < TJ; ++jj) {
        const float4 a4 = sAB[2 * jj + 0];
        const float4 b4 = sAB[2 * jj + 1];
#pragma unroll
        for (int k = 0; k < IT; ++k) {
            float r = fmaf(C2x[k], a4.x, a4.w);
            r = fmaf(C2y[k], a4.y, r);
            r = fmaf(C2z[k], a4.z, r);
            const float t0 = fast_exp2(r + Ai[k]);     // exp(-625*d2)
            float n = fmaf(Nix[k], b4.x, b4.w);
            n = fmaf(Niy[k], b4.y, n);
            n = fmaf(Niz[k], b4.z, n);
            const float en = fast_exp2(n);             // Lj * exp(4*(ndot-1))
            const float t2  = t0 * t0;
            const float t4  = t2 * t2;
            const float t8  = t4 * t4;
            const float t16 = t8 * t8;
            const float t24 = t16 * t8;
            const float t25 = t24 * t0;
            float p = fmaf(0.25f, t16, t4);
            p = fmaf(0.16f, t25, p);
            acc[k] = fmaf(en, p, acc[k]);              // += Lj * en * poly
        }
    }

    // epilogue: apply Li, reduce block, one atomic
    float part = 0.0f;
#pragma unroll
    for (int k = 0; k < IT; ++k) part = fmaf(acc[k], Li[k], part);

#pragma unroll
    for (int off = 32; off; off >>= 1) part += __shfl_xor(part, off);
    if ((tid & 63) == 0) red[tid >> 6] = part;
    __syncthreads();
    if (tid == 0) atomicAdd(out, weight * (red[0] + red[1] + red[2] + red[3]));
}

// ---------------------------------------------------------------------------
extern "C" void kernel_launch(void* const* d_in, const int* in_sizes, int n_in,
                              void* d_out, int out_size, void* d_ws, size_t ws_size,
                              hipStream_t stream) {
    const float* pred  = (const float*)d_in[0];
    const float* targ  = (const float*)d_in[1];
    const int*   faces = (const int*)d_in[2];
    float*       out   = (float*)d_out;
    float4*      ws4   = (float4*)d_ws;   // needs 4*6144*2*16 = 786432 B

    dim3 g1(F_FACES / 256, 2 * BATCH);
    mesh_prep<<<g1, 256, 0, stream>>>(pred, targ, faces, ws4, out);

    dim3 g2(I_TILES * J_CHUNKS, 3 * BATCH);
    varifold_pairs<<<g2, 256, 0, stream>>>(ws4, out);
}

// Round 3
// 139.975 us; speedup vs baseline: 1.3152x; 1.1261x over previous
//
#include <hip/hip_runtime.h>

// Problem constants (from reference setup_inputs)
#define F_FACES 6144
#define VN      5000
#define BATCH   2

// sqrt(625 * log2(e))  -- C pre-scale: exp2 arg = ai + aj + 2*dot(C'i,C'j)
#define SC_F    30.02806022f
// sqrt(4 * log2(e))    -- N pre-scale: ndot term = dot(N'i,N'j)
#define SN_F    2.40224481f
// 4 * log2(e)
#define C4_F    5.7707801635558535f

// Raw v_exp_f32 — measured ~16 cyc/wave64 (1/8 rate); 2 per pair dominate.
__device__ __forceinline__ float fast_exp2(float x) {
    float r;
    asm("v_exp_f32 %0, %1" : "=v"(r) : "v"(x));
    return r;
}

// ---------------------------------------------------------------------------
// Kernel 1: per-face mesh quantities for all 4 meshes (b in {0,1} x {pred,targ})
// Per face, two float4:
//   A = [Cx*SC, Cy*SC, Cz*SC, -|C*SC|^2]
//   B = [Nx*inv*SN, Ny*inv*SN, Nz*inv*SN, log2(L) - 4*log2e]
// B.w folds Lj and the -4*log2e constant into the normal-kernel exp2.
// Also zeroes the output accumulator (stream-ordered before kernel 2).
// ---------------------------------------------------------------------------
__global__ __launch_bounds__(256) void mesh_prep(
    const float* __restrict__ pred, const float* __restrict__ targ,
    const int* __restrict__ faces, float4* __restrict__ ws4,
    float* __restrict__ out)
{
    const int f = blockIdx.x * 256 + threadIdx.x;
    const int m = blockIdx.y;                    // mesh id = b*2 + which
    if (blockIdx.x == 0 && m == 0 && threadIdx.x == 0) out[0] = 0.0f;
    if (f >= F_FACES) return;

    const int b = m >> 1, which = m & 1;
    const float* V = (which ? targ : pred) + b * (VN * 3);

    const int i0 = faces[3 * f + 0];
    const int i1 = faces[3 * f + 1];
    const int i2 = faces[3 * f + 2];

    const float v0x = V[3 * i0 + 0], v0y = V[3 * i0 + 1], v0z = V[3 * i0 + 2];
    const float v1x = V[3 * i1 + 0], v1y = V[3 * i1 + 1], v1z = V[3 * i1 + 2];
    const float v2x = V[3 * i2 + 0], v2y = V[3 * i2 + 1], v2z = V[3 * i2 + 2];

    const float Cx = (v0x + v1x + v2x) * (1.0f / 3.0f);
    const float Cy = (v0y + v1y + v2y) * (1.0f / 3.0f);
    const float Cz = (v0z + v1z + v2z) * (1.0f / 3.0f);

    const float e1x = v1x - v0x, e1y = v1y - v0y, e1z = v1z - v0z;
    const float e2x = v2x - v0x, e2y = v2y - v0y, e2z = v2z - v0z;

    const float Nx = 0.5f * (e1y * e2z - e1z * e2y);
    const float Ny = 0.5f * (e1z * e2x - e1x * e2z);
    const float Nz = 0.5f * (e1x * e2y - e1y * e2x);

    const float l2  = Nx * Nx + Ny * Ny + Nz * Nz + 1e-24f;
    const float L   = sqrtf(l2);
    const float inv = 1.0f / L;

    const float Csx = Cx * SC_F, Csy = Cy * SC_F, Csz = Cz * SC_F;
    const float a   = -(Csx * Csx + Csy * Csy + Csz * Csz);
    const float s   = inv * SN_F;

    const long base = (long)(m * F_FACES + f) * 2;
    ws4[base + 0] = make_float4(Csx, Csy, Csz, a);
    ws4[base + 1] = make_float4(Nx * s, Ny * s, Nz * s, log2f(L) - C4_F);
}

// ---------------------------------------------------------------------------
// Kernel 2: pair sums with ss/tt triangle symmetry.
// grid.x = I_TILES(6) * J_CHUNKS(96) = 576; grid.y = 6 (b x {ss, st, tt}).
// For ss/tt (symmetric K): skip blocks entirely below the diagonal, weight
// pure-upper blocks x2, and per-pair predicate {2,1,0} in straddle blocks
// (j-chunk inside the i-tile's 1024-row range). st runs all blocks.
// Active blocks: 2*(336+576+336) = 2496 (~9.7/CU -> ~32 waves/CU resident).
// Per pair: 16 VALU (2cyc) + 2 v_exp_f32 (~16cyc).
// ---------------------------------------------------------------------------
#define IT        4
#define TJ        64
#define J_CHUNKS  (F_FACES / TJ)          // 96
#define I_TILES   (F_FACES / (256 * IT))  // 6
#define I_ROWS    (256 * IT)              // 1024

__global__ __launch_bounds__(256) void varifold_pairs(
    const float4* __restrict__ ws4, float* __restrict__ out)
{
    __shared__ float4 sAB[2 * TJ];   // interleaved A,B per j-face
    __shared__ float  red[4];

    const int tid = threadIdx.x;
    const int it  = blockIdx.x / J_CHUNKS;   // 0..5
    const int jc  = blockIdx.x % J_CHUNKS;   // 0..95
    const int cb  = blockIdx.y;              // 0..5
    const int b   = cb / 3, c = cb % 3;      // c: 0=ss 1=st 2=tt
    const int m1  = b * 2 + (c == 2 ? 1 : 0);
    const int m2  = b * 2 + (c >= 1 ? 1 : 0);

    const int iBase = it * I_ROWS;
    const int jBase = jc * TJ;

    float wOut;
    bool straddle = false;
    if (c == 1) {
        wOut = -1.0f;                        // -2 * (1/B) * pst
    } else {
        if (jBase + TJ <= iBase) return;     // below diagonal: skip
        if (jBase >= iBase + I_ROWS) {
            wOut = 1.0f;                     // 0.5 * 2 (upper counted twice)
        } else {
            wOut = 0.5f;                     // per-pair factor {2,1,0} applied
            straddle = true;
        }
    }

    const float4* P1 = ws4 + (long)m1 * (F_FACES * 2);
    const float4* P2 = ws4 + (long)m2 * (F_FACES * 2);

    float C2x[IT], C2y[IT], C2z[IT], Ai[IT];
    float Nix[IT], Niy[IT], Niz[IT], Li[IT];
    float acc[IT];
    int   iIdx[IT];

#pragma unroll
    for (int k = 0; k < IT; ++k) {
        const int i = iBase + k * 256 + tid;
        iIdx[k] = i;
        const float4 A  = P1[2 * i + 0];
        const float4 Bv = P1[2 * i + 1];
        C2x[k] = 2.0f * A.x; C2y[k] = 2.0f * A.y; C2z[k] = 2.0f * A.z;
        Ai[k]  = A.w;
        Nix[k] = Bv.x; Niy[k] = Bv.y; Niz[k] = Bv.z;
        Li[k]  = fast_exp2(Bv.w + C4_F);   // recover Li
        acc[k] = 0.0f;
    }

    // stage this block's j-tile: 2*TJ = 128 float4
    if (tid < 2 * TJ) sAB[tid] = P2[2 * jBase + tid];
    __syncthreads();

    if (!straddle) {
#pragma unroll 4
        for (int jj = 0; jj < TJ; ++jj) {
            const float4 a4 = sAB[2 * jj + 0];
            const float4 b4 = sAB[2 * jj + 1];
#pragma unroll
            for (int k = 0; k < IT; ++k) {
                float r = fmaf(C2x[k], a4.x, a4.w);
                r = fmaf(C2y[k], a4.y, r);
                r = fmaf(C2z[k], a4.z, r);
                const float t0 = fast_exp2(r + Ai[k]);   // exp(-625*d2)
                float n = fmaf(Nix[k], b4.x, b4.w);
                n = fmaf(Niy[k], b4.y, n);
                n = fmaf(Niz[k], b4.z, n);
                const float en = fast_exp2(n);           // Lj*exp(4*(ndot-1))
                const float t2  = t0 * t0;
                const float t4  = t2 * t2;
                const float t8  = t4 * t4;
                const float t16 = t8 * t8;
                const float t24 = t16 * t8;
                const float t25 = t24 * t0;
                float p = fmaf(0.25f, t16, t4);
                p = fmaf(0.16f, t25, p);
                acc[k] = fmaf(en, p, acc[k]);
            }
        }
    } else {
#pragma unroll 4
        for (int jj = 0; jj < TJ; ++jj) {
            const float4 a4 = sAB[2 * jj + 0];
            const float4 b4 = sAB[2 * jj + 1];
            const int j = jBase + jj;
#pragma unroll
            for (int k = 0; k < IT; ++k) {
                float r = fmaf(C2x[k], a4.x, a4.w);
                r = fmaf(C2y[k], a4.y, r);
                r = fmaf(C2z[k], a4.z, r);
                const float t0 = fast_exp2(r + Ai[k]);
                float n = fmaf(Nix[k], b4.x, b4.w);
                n = fmaf(Niy[k], b4.y, n);
                n = fmaf(Niz[k], b4.z, n);
                const float en = fast_exp2(n);
                const float t2  = t0 * t0;
                const float t4  = t2 * t2;
                const float t8  = t4 * t4;
                const float t16 = t8 * t8;
                const float t24 = t16 * t8;
                const float t25 = t24 * t0;
                float p = fmaf(0.25f, t16, t4);
                p = fmaf(0.16f, t25, p);
                // pair factor: 2 if j>i (upper), 1 if j==i (diag), 0 if j<i
                float f = (j > iIdx[k]) ? 2.0f : 0.0f;
                f = (j == iIdx[k]) ? 1.0f : f;
                acc[k] = fmaf(f * en, p, acc[k]);
            }
        }
    }

    // epilogue: apply Li, reduce block, one atomic
    float part = 0.0f;
#pragma unroll
    for (int k = 0; k < IT; ++k) part = fmaf(acc[k], Li[k], part);

#pragma unroll
    for (int off = 32; off; off >>= 1) part += __shfl_xor(part, off);
    if ((tid & 63) == 0) red[tid >> 6] = part;
    __syncthreads();
    if (tid == 0) atomicAdd(out, wOut * (red[0] + red[1] + red[2] + red[3]));
}

// ---------------------------------------------------------------------------
extern "C" void kernel_launch(void* const* d_in, const int* in_sizes, int n_in,
                              void* d_out, int out_size, void* d_ws, size_t ws_size,
                              hipStream_t stream) {
    const float* pred  = (const float*)d_in[0];
    const float* targ  = (const float*)d_in[1];
    const int*   faces = (const int*)d_in[2];
    float*       out   = (float*)d_out;
    float4*      ws4   = (float4*)d_ws;   // needs 4*6144*2*16 = 786432 B

    dim3 g1(F_FACES / 256, 2 * BATCH);
    mesh_prep<<<g1, 256, 0, stream>>>(pred, targ, faces, ws4, out);

    dim3 g2(I_TILES * J_CHUNKS, 3 * BATCH);
    varifold_pairs<<<g2, 256, 0, stream>>>(ws4, out);
}

// Round 4
// 136.086 us; speedup vs baseline: 1.3527x; 1.0286x over previous
//
#include <hip/hip_runtime.h>

// Problem constants (from reference setup_inputs)
#define F_FACES 6144
#define VN      5000
#define BATCH   2

// sqrt(625 * log2(e))  -- C pre-scale: exp2 arg = ai + aj + 2*dot(C'i,C'j)
#define SC_F    30.02806022f
// sqrt(4 * log2(e))    -- N pre-scale: ndot term = dot(N'i,N'j)
#define SN_F    2.40224481f
// 4 * log2(e)
#define C4_F    5.7707801635558535f

// Raw v_exp_f32 — measured ~16 cyc/wave64; 2 per pair = half the serial demand.
__device__ __forceinline__ float fast_exp2(float x) {
    float r;
    asm("v_exp_f32 %0, %1" : "=v"(r) : "v"(x));
    return r;
}

// ---------------------------------------------------------------------------
// Kernel 1: per-face mesh quantities for all 4 meshes (b in {0,1} x {pred,targ})
// Per face, two float4:
//   A = [Cx*SC, Cy*SC, Cz*SC, -|C*SC|^2]
//   B = [Nx*inv*SN, Ny*inv*SN, Nz*inv*SN, log2(L) - 4*log2e]
// B.w folds Lj and the -4*log2e constant into the normal-kernel exp2.
// Also zeroes the output accumulator (stream-ordered before kernel 2).
// ---------------------------------------------------------------------------
__global__ __launch_bounds__(256) void mesh_prep(
    const float* __restrict__ pred, const float* __restrict__ targ,
    const int* __restrict__ faces, float4* __restrict__ ws4,
    float* __restrict__ out)
{
    const int f = blockIdx.x * 256 + threadIdx.x;
    const int m = blockIdx.y;                    // mesh id = b*2 + which
    if (blockIdx.x == 0 && m == 0 && threadIdx.x == 0) out[0] = 0.0f;
    if (f >= F_FACES) return;

    const int b = m >> 1, which = m & 1;
    const float* V = (which ? targ : pred) + b * (VN * 3);

    const int i0 = faces[3 * f + 0];
    const int i1 = faces[3 * f + 1];
    const int i2 = faces[3 * f + 2];

    const float v0x = V[3 * i0 + 0], v0y = V[3 * i0 + 1], v0z = V[3 * i0 + 2];
    const float v1x = V[3 * i1 + 0], v1y = V[3 * i1 + 1], v1z = V[3 * i1 + 2];
    const float v2x = V[3 * i2 + 0], v2y = V[3 * i2 + 1], v2z = V[3 * i2 + 2];

    const float Cx = (v0x + v1x + v2x) * (1.0f / 3.0f);
    const float Cy = (v0y + v1y + v2y) * (1.0f / 3.0f);
    const float Cz = (v0z + v1z + v2z) * (1.0f / 3.0f);

    const float e1x = v1x - v0x, e1y = v1y - v0y, e1z = v1z - v0z;
    const float e2x = v2x - v0x, e2y = v2y - v0y, e2z = v2z - v0z;

    const float Nx = 0.5f * (e1y * e2z - e1z * e2y);
    const float Ny = 0.5f * (e1z * e2x - e1x * e2z);
    const float Nz = 0.5f * (e1x * e2y - e1y * e2x);

    const float l2  = Nx * Nx + Ny * Ny + Nz * Nz + 1e-24f;
    const float L   = sqrtf(l2);
    const float inv = 1.0f / L;

    const float Csx = Cx * SC_F, Csy = Cy * SC_F, Csz = Cz * SC_F;
    const float a   = -(Csx * Csx + Csy * Csy + Csz * Csz);
    const float s   = inv * SN_F;

    const long base = (long)(m * F_FACES + f) * 2;
    ws4[base + 0] = make_float4(Csx, Csy, Csz, a);
    ws4[base + 1] = make_float4(Nx * s, Ny * s, Nz * s, log2f(L) - C4_F);
}

// ---------------------------------------------------------------------------
// Kernel 2: pair sums, active-blocks-only enumeration.
// 128-thread blocks (2 waves), IT=4 -> i-tile = 512 rows; TJ = 64 j-faces.
// Block set (1-D, no dead blocks):
//   [0, 2304): st (c=1), b = idx/1152, lin -> (it, jc) dense 12x96
//   [2304, 4800): ss/tt triangles, q = (idx-2304)/624 -> {ss b0, ss b1, tt b0,
//     tt b1}; lin in [0,624) decodes (it, jc>=8*it) via cum(it)=96it-4it(it-1)
// Straddle blocks (jc in [8it, 8it+8)) apply per-pair factor {2,1,0}.
// Per pair: 16 VALU (2cyc) + 2 v_exp_f32 (~16cyc) -> 64 cyc/wave-iter serial.
// ---------------------------------------------------------------------------
#define IT        4
#define TJ        64
#define BLK       128
#define J_CHUNKS  (F_FACES / TJ)          // 96
#define I_ROWS    (BLK * IT)              // 512
#define I_TILES   (F_FACES / I_ROWS)      // 12
#define N_ST      (I_TILES * J_CHUNKS)    // 1152 per b
#define N_TRI     624                     // sum_{it<12} (96 - 8*it)
#define N_BLOCKS  (2 * N_ST + 4 * N_TRI)  // 4800

__global__ __launch_bounds__(BLK) void varifold_pairs(
    const float4* __restrict__ ws4, float* __restrict__ out)
{
    __shared__ float4 sAB[2 * TJ];   // interleaved A,B per j-face
    __shared__ float  red[2];

    const int tid = threadIdx.x;

    // ---- block decode (scalar, uniform) ----
    int c, b, it, jc;
    {
        const int bi = blockIdx.x;
        if (bi < 2 * N_ST) {
            c = 1; b = bi / N_ST;
            const int lin = bi % N_ST;
            it = lin / J_CHUNKS; jc = lin % J_CHUNKS;
        } else {
            const int r = bi - 2 * N_ST;
            const int q = r / N_TRI;
            c = (q & 2) ? 2 : 0; b = q & 1;
            int lin = r - q * N_TRI;
            it = 0;
            int w = J_CHUNKS;                 // active chunks for tile it
            while (lin >= w) { lin -= w; ++it; w -= 8; }
            jc = 8 * it + lin;
        }
    }

    const int m1 = b * 2 + (c == 2 ? 1 : 0);
    const int m2 = b * 2 + (c >= 1 ? 1 : 0);
    const int iBase = it * I_ROWS;
    const int jBase = jc * TJ;

    const bool straddle = (c != 1) && (jc < 8 * (it + 1));
    const float wOut = (c == 1) ? -1.0f : (straddle ? 0.5f : 1.0f);

    const float4* P1 = ws4 + (long)m1 * (F_FACES * 2);
    const float4* P2 = ws4 + (long)m2 * (F_FACES * 2);

    float C2x[IT], C2y[IT], C2z[IT], Ai[IT];
    float Nix[IT], Niy[IT], Niz[IT], Li[IT];
    float acc[IT];
    int   iIdx[IT];

#pragma unroll
    for (int k = 0; k < IT; ++k) {
        const int i = iBase + k * BLK + tid;
        iIdx[k] = i;
        const float4 A  = P1[2 * i + 0];
        const float4 Bv = P1[2 * i + 1];
        C2x[k] = 2.0f * A.x; C2y[k] = 2.0f * A.y; C2z[k] = 2.0f * A.z;
        Ai[k]  = A.w;
        Nix[k] = Bv.x; Niy[k] = Bv.y; Niz[k] = Bv.z;
        Li[k]  = fast_exp2(Bv.w + C4_F);   // recover Li
        acc[k] = 0.0f;
    }

    // stage this block's j-tile: 2*TJ = 128 float4 = one per thread
    sAB[tid] = P2[2 * jBase + tid];
    __syncthreads();

    if (!straddle) {
#pragma unroll 4
        for (int jj = 0; jj < TJ; ++jj) {
            const float4 a4 = sAB[2 * jj + 0];
            const float4 b4 = sAB[2 * jj + 1];
#pragma unroll
            for (int k = 0; k < IT; ++k) {
                float r = fmaf(C2x[k], a4.x, a4.w);
                r = fmaf(C2y[k], a4.y, r);
                r = fmaf(C2z[k], a4.z, r);
                const float t0 = fast_exp2(r + Ai[k]);   // exp(-625*d2)
                float n = fmaf(Nix[k], b4.x, b4.w);
                n = fmaf(Niy[k], b4.y, n);
                n = fmaf(Niz[k], b4.z, n);
                const float en = fast_exp2(n);           // Lj*exp(4*(ndot-1))
                const float t2  = t0 * t0;
                const float t4  = t2 * t2;
                const float t8  = t4 * t4;
                const float t16 = t8 * t8;
                const float t24 = t16 * t8;
                const float t25 = t24 * t0;
                float p = fmaf(0.25f, t16, t4);
                p = fmaf(0.16f, t25, p);
                acc[k] = fmaf(en, p, acc[k]);
            }
        }
    } else {
#pragma unroll 4
        for (int jj = 0; jj < TJ; ++jj) {
            const float4 a4 = sAB[2 * jj + 0];
            const float4 b4 = sAB[2 * jj + 1];
            const int j = jBase + jj;
#pragma unroll
            for (int k = 0; k < IT; ++k) {
                float r = fmaf(C2x[k], a4.x, a4.w);
                r = fmaf(C2y[k], a4.y, r);
                r = fmaf(C2z[k], a4.z, r);
                const float t0 = fast_exp2(r + Ai[k]);
                float n = fmaf(Nix[k], b4.x, b4.w);
                n = fmaf(Niy[k], b4.y, n);
                n = fmaf(Niz[k], b4.z, n);
                const float en = fast_exp2(n);
                const float t2  = t0 * t0;
                const float t4  = t2 * t2;
                const float t8  = t4 * t4;
                const float t16 = t8 * t8;
                const float t24 = t16 * t8;
                const float t25 = t24 * t0;
                float p = fmaf(0.25f, t16, t4);
                p = fmaf(0.16f, t25, p);
                // pair factor: 2 if j>i (upper), 1 if j==i (diag), 0 if j<i
                float f = (j > iIdx[k]) ? 2.0f : 0.0f;
                f = (j == iIdx[k]) ? 1.0f : f;
                acc[k] = fmaf(f * en, p, acc[k]);
            }
        }
    }

    // epilogue: apply Li, reduce block (2 waves), one atomic
    float part = 0.0f;
#pragma unroll
    for (int k = 0; k < IT; ++k) part = fmaf(acc[k], Li[k], part);

#pragma unroll
    for (int off = 32; off; off >>= 1) part += __shfl_xor(part, off);
    if ((tid & 63) == 0) red[tid >> 6] = part;
    __syncthreads();
    if (tid == 0) atomicAdd(out, wOut * (red[0] + red[1]));
}

// ---------------------------------------------------------------------------
extern "C" void kernel_launch(void* const* d_in, const int* in_sizes, int n_in,
                              void* d_out, int out_size, void* d_ws, size_t ws_size,
                              hipStream_t stream) {
    const float* pred  = (const float*)d_in[0];
    const float* targ  = (const float*)d_in[1];
    const int*   faces = (const int*)d_in[2];
    float*       out   = (float*)d_out;
    float4*      ws4   = (float4*)d_ws;   // needs 4*6144*2*16 = 786432 B

    dim3 g1(F_FACES / 256, 2 * BATCH);
    mesh_prep<<<g1, 256, 0, stream>>>(pred, targ, faces, ws4, out);

    varifold_pairs<<<dim3(N_BLOCKS), dim3(BLK), 0, stream>>>(ws4, out);
}

// Round 5
// 130.208 us; speedup vs baseline: 1.4138x; 1.0451x over previous
//
#include <hip/hip_runtime.h>

// Problem constants (from reference setup_inputs)
#define F_FACES 6144
#define VN      5000

// sqrt(625 * log2(e))  -- C pre-scale: exp2 arg = ai + aj + 2*dot(C'i,C'j)
#define SC_F    30.02806022f
// sqrt(4 * log2(e))    -- N pre-scale: ndot term = dot(N'i,N'j)
#define SN_F    2.40224481f
// 4 * log2(e)
#define C4_F    5.7707801635558535f

// Raw v_exp_f32 — ~16 cyc/wave64 measured; 2 per pair = half the issue demand.
__device__ __forceinline__ float fast_exp2(float x) {
    float r;
    asm("v_exp_f32 %0, %1" : "=v"(r) : "v"(x));
    return r;
}

// ws layout: [0, 786432) mesh float4 pairs (4 meshes x 6144 faces x 2)
//            [786432, +4096) 64 accumulator cells, stride 16 floats (64 B)
#define CELLS_OFF_FLOATS (4 * F_FACES * 2 * 4)   // 196608 floats

// ---------------------------------------------------------------------------
// Kernel 1: per-face quantities for 4 meshes; zeroes the 64 partial cells.
//   A = [Cx*SC, Cy*SC, Cz*SC, -|C*SC|^2]
//   B = [Nx*inv*SN, Ny*inv*SN, Nz*inv*SN, log2(L) - 4*log2e]
// ---------------------------------------------------------------------------
__global__ __launch_bounds__(256) void mesh_prep(
    const float* __restrict__ pred, const float* __restrict__ targ,
    const int* __restrict__ faces, float4* __restrict__ ws4,
    float* __restrict__ cells)
{
    const int f = blockIdx.x * 256 + threadIdx.x;
    const int m = blockIdx.y;                    // mesh id = b*2 + which
    if (blockIdx.x == 0 && m == 0 && threadIdx.x < 64)
        cells[threadIdx.x * 16] = 0.0f;
    if (f >= F_FACES) return;

    const int b = m >> 1, which = m & 1;
    const float* V = (which ? targ : pred) + b * (VN * 3);

    const int i0 = faces[3 * f + 0];
    const int i1 = faces[3 * f + 1];
    const int i2 = faces[3 * f + 2];

    const float v0x = V[3 * i0 + 0], v0y = V[3 * i0 + 1], v0z = V[3 * i0 + 2];
    const float v1x = V[3 * i1 + 0], v1y = V[3 * i1 + 1], v1z = V[3 * i1 + 2];
    const float v2x = V[3 * i2 + 0], v2y = V[3 * i2 + 1], v2z = V[3 * i2 + 2];

    const float Cx = (v0x + v1x + v2x) * (1.0f / 3.0f);
    const float Cy = (v0y + v1y + v2y) * (1.0f / 3.0f);
    const float Cz = (v0z + v1z + v2z) * (1.0f / 3.0f);

    const float e1x = v1x - v0x, e1y = v1y - v0y, e1z = v1z - v0z;
    const float e2x = v2x - v0x, e2y = v2y - v0y, e2z = v2z - v0z;

    const float Nx = 0.5f * (e1y * e2z - e1z * e2y);
    const float Ny = 0.5f * (e1z * e2x - e1x * e2z);
    const float Nz = 0.5f * (e1x * e2y - e1y * e2x);

    const float l2  = Nx * Nx + Ny * Ny + Nz * Nz + 1e-24f;
    const float L   = sqrtf(l2);
    const float inv = 1.0f / L;

    const float Csx = Cx * SC_F, Csy = Cy * SC_F, Csz = Cz * SC_F;
    const float a   = -(Csx * Csx + Csy * Csy + Csz * Csz);
    const float s   = inv * SN_F;

    const long base = (long)(m * F_FACES + f) * 2;
    ws4[base + 0] = make_float4(Csx, Csy, Csz, a);
    ws4[base + 1] = make_float4(Nx * s, Ny * s, Nz * s, log2f(L) - C4_F);
}

// ---------------------------------------------------------------------------
// Kernel 2: pair sums over a flattened, perfectly balanced column space.
// Column = (band, j-face); band = 512-row i-band of one (c,b,it).
//   tri bands (c in {ss,tt}): j in [512*it, 6144), width 6144-512*it
//   st  bands (c=st):         j in [0, 6144)
// Total columns = 4*39936 + 24*6144 = 307200 = 12288 blocks * 25 cols.
// Identical work per block; 12288 divisible by any plausible resident-block
// capacity (1024/2048/3072/4096) -> exact rounds, no ragged tail.
// Straddle (first 512 cols of a tri band) applies per-pair factor {2,1,0}.
// ---------------------------------------------------------------------------
#define BLK       128
#define IT        4
#define I_ROWS    (BLK * IT)              // 512
#define I_TILES   (F_FACES / I_ROWS)      // 12
#define W_TRI_Q   39936                   // per (c,b) triangle columns
#define TRI_TOTAL (4 * W_TRI_Q)           // 159744
#define TOTAL_COLS 307200
#define N_BLOCKS  12288
#define CPB       25                      // columns per block

__global__ __launch_bounds__(BLK, 8) void varifold_pairs(
    const float4* __restrict__ ws4, float* __restrict__ cells)
{
    __shared__ float4 sAB[2 * CPB];
    __shared__ float  red[2];

    const int tid = threadIdx.x;
    int col = blockIdx.x * CPB;
    int remaining = CPB;
    float total = 0.0f;

    int cur_key = -1;   // (m1 * 16 + it) of cached i-state
    float C2x[IT], C2y[IT], C2z[IT], Ai[IT];
    float Nix[IT], Niy[IT], Niz[IT], Li[IT];
    float acc[IT];

    while (remaining > 0) {
        // ---- decode col -> (c, b, it, j, bandLeft, straddle) ----
        int c, b, it, j, r, bandLeft;
        if (col < TRI_TOTAL) {
            const int q = col / W_TRI_Q;         // 0..3
            r = col - q * W_TRI_Q;
            c = (q >> 1) ? 2 : 0; b = q & 1;
            it = 0;
            int w = F_FACES;
            while (r >= w) { r -= w; ++it; w -= I_ROWS; }
            j = it * I_ROWS + r;
            bandLeft = w - r;
        } else {
            const int lin = col - TRI_TOTAL;
            const int band = lin / F_FACES;
            r = lin - band * F_FACES;
            j = r;
            b = band / I_TILES; it = band - (band / I_TILES) * I_TILES;
            c = 1;
            bandLeft = F_FACES - r;
        }
        const bool strad = (c != 1) && (r < I_ROWS);
        int segLen = min(remaining, bandLeft);
        if (strad) segLen = min(segLen, I_ROWS - r);
        const float wOut = (c == 1) ? -1.0f : (strad ? 0.5f : 1.0f);
        const int m1 = 2 * b + (c == 2 ? 1 : 0);
        const int m2 = 2 * b + (c >= 1 ? 1 : 0);
        const float4* P1 = ws4 + (long)m1 * (F_FACES * 2);
        const float4* P2 = ws4 + (long)m2 * (F_FACES * 2);
        const int iBase = it * I_ROWS;

        // ---- (re)load i-state if band changed ----
        const int key = m1 * 16 + it;
        if (key != cur_key) {
            cur_key = key;
#pragma unroll
            for (int k = 0; k < IT; ++k) {
                const int i = iBase + k * BLK + tid;
                const float4 A  = P1[2 * i + 0];
                const float4 Bv = P1[2 * i + 1];
                C2x[k] = 2.0f * A.x; C2y[k] = 2.0f * A.y; C2z[k] = 2.0f * A.z;
                Ai[k]  = A.w;
                Nix[k] = Bv.x; Niy[k] = Bv.y; Niz[k] = Bv.z;
                Li[k]  = fast_exp2(Bv.w + C4_F);
            }
        }
#pragma unroll
        for (int k = 0; k < IT; ++k) acc[k] = 0.0f;

        // ---- stage segment's j-faces ----
        __syncthreads();   // previous segment done reading sAB
        if (tid < 2 * segLen) sAB[tid] = P2[2 * j + tid];
        __syncthreads();

        if (!strad) {
            for (int jj = 0; jj < segLen; ++jj) {
                const float4 a4 = sAB[2 * jj + 0];
                const float4 b4 = sAB[2 * jj + 1];
#pragma unroll
                for (int k = 0; k < IT; ++k) {
                    float rr = fmaf(C2x[k], a4.x, a4.w);
                    rr = fmaf(C2y[k], a4.y, rr);
                    rr = fmaf(C2z[k], a4.z, rr);
                    const float t0 = fast_exp2(rr + Ai[k]);  // exp(-625 d2)
                    float n = fmaf(Nix[k], b4.x, b4.w);
                    n = fmaf(Niy[k], b4.y, n);
                    n = fmaf(Niz[k], b4.z, n);
                    const float en = fast_exp2(n);           // Lj*exp(4(nd-1))
                    const float t2  = t0 * t0;
                    const float t4  = t2 * t2;
                    const float t8  = t4 * t4;
                    const float t16 = t8 * t8;
                    const float t24 = t16 * t8;
                    const float t25 = t24 * t0;
                    float p = fmaf(0.25f, t16, t4);
                    p = fmaf(0.16f, t25, p);
                    acc[k] = fmaf(en, p, acc[k]);
                }
            }
        } else {
            for (int jj = 0; jj < segLen; ++jj) {
                const float4 a4 = sAB[2 * jj + 0];
                const float4 b4 = sAB[2 * jj + 1];
                const int jg = j + jj;
#pragma unroll
                for (int k = 0; k < IT; ++k) {
                    const int i = iBase + k * BLK + tid;
                    float rr = fmaf(C2x[k], a4.x, a4.w);
                    rr = fmaf(C2y[k], a4.y, rr);
                    rr = fmaf(C2z[k], a4.z, rr);
                    const float t0 = fast_exp2(rr + Ai[k]);
                    float n = fmaf(Nix[k], b4.x, b4.w);
                    n = fmaf(Niy[k], b4.y, n);
                    n = fmaf(Niz[k], b4.z, n);
                    const float en = fast_exp2(n);
                    const float t2  = t0 * t0;
                    const float t4  = t2 * t2;
                    const float t8  = t4 * t4;
                    const float t16 = t8 * t8;
                    const float t24 = t16 * t8;
                    const float t25 = t24 * t0;
                    float p = fmaf(0.25f, t16, t4);
                    p = fmaf(0.16f, t25, p);
                    float fw = (jg > i) ? 2.0f : 0.0f;       // upper x2
                    fw = (jg == i) ? 1.0f : fw;              // diagonal x1
                    acc[k] = fmaf(fw * en, p, acc[k]);
                }
            }
        }

        // fold segment into thread total with segment weight
        float part = 0.0f;
#pragma unroll
        for (int k = 0; k < IT; ++k) part = fmaf(acc[k], Li[k], part);
        total = fmaf(wOut, part, total);

        col += segLen; remaining -= segLen;
    }

    // block reduce, one spread atomic per block
#pragma unroll
    for (int off = 32; off; off >>= 1) total += __shfl_xor(total, off);
    if ((tid & 63) == 0) red[tid >> 6] = total;
    __syncthreads();
    if (tid == 0)
        atomicAdd(&cells[(blockIdx.x & 63) * 16], red[0] + red[1]);
}

// ---------------------------------------------------------------------------
// Kernel 3: sum the 64 cells -> out[0].
// ---------------------------------------------------------------------------
__global__ __launch_bounds__(64) void finalize_sum(
    const float* __restrict__ cells, float* __restrict__ out)
{
    float v = cells[threadIdx.x * 16];
#pragma unroll
    for (int off = 32; off; off >>= 1) v += __shfl_xor(v, off);
    if (threadIdx.x == 0) out[0] = v;
}

// ---------------------------------------------------------------------------
extern "C" void kernel_launch(void* const* d_in, const int* in_sizes, int n_in,
                              void* d_out, int out_size, void* d_ws, size_t ws_size,
                              hipStream_t stream) {
    const float* pred  = (const float*)d_in[0];
    const float* targ  = (const float*)d_in[1];
    const int*   faces = (const int*)d_in[2];
    float*       out   = (float*)d_out;
    float4*      ws4   = (float4*)d_ws;                       // 786432 B
    float*       cells = (float*)d_ws + CELLS_OFF_FLOATS;     // +4 KB

    dim3 g1(F_FACES / 256, 4);
    mesh_prep<<<g1, 256, 0, stream>>>(pred, targ, faces, ws4, cells);

    varifold_pairs<<<dim3(N_BLOCKS), dim3(BLK), 0, stream>>>(ws4, cells);

    finalize_sum<<<dim3(1), dim3(64), 0, stream>>>(cells, out);
}